// Round 7
// baseline (531.518 us; speedup 1.0000x reference)
//
#include <hip/hip_runtime.h>

typedef __attribute__((ext_vector_type(8)))  short short8;   // 8 x bf16 fragment
typedef __attribute__((ext_vector_type(4)))  float f32x4;
typedef __attribute__((ext_vector_type(16))) float f32x16;

constexpr int N_ROWS = 131072;
constexpr int K_CB   = 4096;
constexpr int D_DIM  = 64;
constexpr float EPS_M = 1.25e-3f;   // margin in m-units (= 2.5e-3 in d = |x-c|^2 units)

// ---- ws layout (bytes) ----
constexpr size_t CTR_OFF   = 0;                         // int counter
constexpr size_t CSQ_OFF   = 64;                        // 4096 f32 (|c|^2, for repair)
constexpr size_t CB4_OFF   = CSQ_OFF + 16384;           // 4096 x 4 f32 (-0.5|c|^2 replicated)
constexpr size_t CBH_OFF   = CB4_OFF + 65536;           // 4096*64 bf16 hi, PLAIN layout
constexpr size_t CBL_OFF   = CBH_OFF + 524288;          // lo plane, PLAIN layout
constexpr size_t LIST_OFF  = CBL_OFF + 524288;          // flagged-row list

#define MFMA32(a, b, c) __builtin_amdgcn_mfma_f32_32x32x16_bf16((a), (b), (c), 0, 0, 0)

__device__ __forceinline__ unsigned short f2bf(float f) {
    unsigned int u = __builtin_bit_cast(unsigned int, f);
    u = (u + 0x7fffu + ((u >> 16) & 1u)) >> 16;   // RTNE
    return (unsigned short)u;
}
__device__ __forceinline__ float bf2f(unsigned short h) {
    return __builtin_bit_cast(float, ((unsigned int)h) << 16);
}

// swizzled 16B fragment read from the A LDS tile; chunk (2*ks+g) XOR (row&7)
__device__ __forceinline__ short8 ldfrag32(const unsigned char* base, int row, int g, int ks) {
    const int slot = ((2 * ks + g) ^ (row & 7));
    uint4 v = *(const uint4*)(base + row * 128 + slot * 16);
    return __builtin_bit_cast(short8, v);
}

// ---- prep: codebook squared norms + replicated -0.5*csq; counter init ----
__global__ __launch_bounds__(256)
void prep_csq(const float* __restrict__ cb, float* __restrict__ csq,
              float4* __restrict__ cbias4, int* __restrict__ counter) {
    const int k = blockIdx.x * 256 + threadIdx.x;
    if (k == 0) *counter = 0;
    const float4* row = (const float4*)(cb + (size_t)k * D_DIM);
    float s = 0.f;
    #pragma unroll
    for (int i = 0; i < 16; ++i) {
        float4 v = row[i];
        s = fmaf(v.x, v.x, s); s = fmaf(v.y, v.y, s);
        s = fmaf(v.z, v.z, s); s = fmaf(v.w, v.w, s);
    }
    csq[k] = s;
    const float n = -0.5f * s;
    cbias4[k] = make_float4(n, n, n, n);
}

// ---- prep: split cb into hi/lo bf16 planes, PLAIN layout (no swizzle) ----
__global__ __launch_bounds__(256)
void prep_split(const float* __restrict__ cb, unsigned char* __restrict__ cbh,
                unsigned char* __restrict__ cbl) {
    const int id  = blockIdx.x * 256 + threadIdx.x;   // 32768 = 4096 rows * 8 chunks
    const int row = id >> 3, s = id & 7;
    const float4* src = (const float4*)(cb + (size_t)row * D_DIM + s * 8);
    float4 v0 = src[0], v1 = src[1];
    float f[8] = {v0.x, v0.y, v0.z, v0.w, v1.x, v1.y, v1.z, v1.w};
    unsigned int hw[4], lw[4];
    #pragma unroll
    for (int i = 0; i < 4; ++i) {
        unsigned short h0 = f2bf(f[2*i]),     l0 = f2bf(f[2*i]     - bf2f(h0));
        unsigned short h1 = f2bf(f[2*i + 1]), l1 = f2bf(f[2*i + 1] - bf2f(h1));
        hw[i] = (unsigned int)h0 | ((unsigned int)h1 << 16);
        lw[i] = (unsigned int)l0 | ((unsigned int)l1 << 16);
    }
    *(uint4*)(cbh + (size_t)row * 128 + s * 16) = make_uint4(hw[0], hw[1], hw[2], hw[3]);
    *(uint4*)(cbl + (size_t)row * 128 + s * 16) = make_uint4(lw[0], lw[1], lw[2], lw[3]);
}

// ---- main: barrier-free K-loop, B streamed from L2, reg double-buffered ----
__global__ __launch_bounds__(256, 2)
void vq_main_mfma(const float* __restrict__ z,
                  const float* __restrict__ cb,
                  const unsigned char* __restrict__ cbh,
                  const unsigned char* __restrict__ cbl,
                  const float* __restrict__ cbias4,
                  int* __restrict__ list,
                  int* __restrict__ counter, float* __restrict__ out) {
    __shared__ __align__(16) unsigned char sm[32768];   // A hi 16K | A lo 16K (dead after frag read)
    const int t = threadIdx.x, lane = t & 63, wid = t >> 6;
    const int g = lane >> 5, colv = lane & 31;
    const int n0 = blockIdx.x * 128;
    const int wbase = wid * 32;

    // stage A tile (128 rows of z) hi/lo swizzled into LDS (round-6 verified path)
    #pragma unroll
    for (int p = 0; p < 4; ++p) {
        const int id = t + p * 256;          // 1024 = 128 rows * 8 chunks
        const int row = id >> 3, s = id & 7;
        const float4* src = (const float4*)(z + (size_t)(n0 + row) * D_DIM + s * 8);
        float4 v0 = src[0], v1 = src[1];
        float f[8] = {v0.x, v0.y, v0.z, v0.w, v1.x, v1.y, v1.z, v1.w};
        unsigned int hw[4], lw[4];
        #pragma unroll
        for (int i = 0; i < 4; ++i) {
            unsigned short h0 = f2bf(f[2*i]),     l0 = f2bf(f[2*i]     - bf2f(h0));
            unsigned short h1 = f2bf(f[2*i + 1]), l1 = f2bf(f[2*i + 1] - bf2f(h1));
            hw[i] = (unsigned int)h0 | ((unsigned int)h1 << 16);
            lw[i] = (unsigned int)l0 | ((unsigned int)l1 << 16);
        }
        const int slot = s ^ (row & 7);
        *(uint4*)(&sm[row * 128 + slot * 16])         = make_uint4(hw[0], hw[1], hw[2], hw[3]);
        *(uint4*)(&sm[16384 + row * 128 + slot * 16]) = make_uint4(lw[0], lw[1], lw[2], lw[3]);
    }
    __syncthreads();

    // A fragments: row = wbase + colv, 4 k-steps of 16
    short8 ah[4], al[4];
    {
        const int arow = wbase + colv;
        #pragma unroll
        for (int ks = 0; ks < 4; ++ks) {
            ah[ks] = ldfrag32(&sm[0],     arow, g, ks);
            al[ks] = ldfrag32(&sm[16384], arow, g, ks);
        }
    }
    __syncthreads();   // all waves done with A LDS; region dead (reused for bidx later)

    // per-lane exact top-2 + index
    float b1[16], b2[16]; int i1[16];
    #pragma unroll
    for (int j = 0; j < 16; ++j) {
        b1[j] = -__builtin_inff(); b2[j] = -__builtin_inff(); i1[j] = 0;
    }

    // per-lane B base: code row = step*32 + colv; chunk j = 2*ks + g -> ks*32 + g*16
    const unsigned char* bh_base = cbh + (size_t)colv * 128 + g * 16;
    const unsigned char* bl_base = cbl + (size_t)colv * 128 + g * 16;
    const unsigned char* cb_base = (const unsigned char*)cbias4 + (size_t)colv * 16;

    short8 bhA[4], blA[4], bhB[4], blB[4];
    f32x4 cbA, cbB;

    // prologue: load step 0 into A buffers
    {
        const unsigned char* ph = bh_base;
        const unsigned char* pl = bl_base;
        #pragma unroll
        for (int ks = 0; ks < 4; ++ks) {
            bhA[ks] = *(const short8*)(ph + ks * 32);
            blA[ks] = *(const short8*)(pl + ks * 32);
        }
        cbA = *(const f32x4*)(cb_base);
    }

    // 128 steps of 32 codes; unroll 2 for static reg double-buffering
    for (int s = 0; s < 128; s += 2) {
        // ---- even step: compute on A, load s+1 into B ----
        {
            const unsigned char* ph = bh_base + (size_t)(s + 1) * 4096;
            const unsigned char* pl = bl_base + (size_t)(s + 1) * 4096;
            #pragma unroll
            for (int ks = 0; ks < 4; ++ks) {
                bhB[ks] = *(const short8*)(ph + ks * 32);
                blB[ks] = *(const short8*)(pl + ks * 32);
            }
            cbB = *(const f32x4*)(cb_base + (size_t)(s + 1) * 512);

            f32x16 acc;
            #pragma unroll
            for (int q = 0; q < 16; ++q) acc[q] = cbA[q & 3];
            #pragma unroll
            for (int ks = 0; ks < 4; ++ks) acc = MFMA32(ah[ks], bhA[ks], acc);  // xh*ch
            #pragma unroll
            for (int ks = 0; ks < 4; ++ks) acc = MFMA32(al[ks], bhA[ks], acc);  // xl*ch
            #pragma unroll
            for (int ks = 0; ks < 4; ++ks) acc = MFMA32(ah[ks], blA[ks], acc);  // xh*cl

            const int idxv = s * 32 + colv;
            #pragma unroll
            for (int j = 0; j < 16; ++j) {
                const float a = acc[j];
                const bool gt = a > b1[j];
                b2[j] = fmaxf(b2[j], fminf(b1[j], a));
                b1[j] = gt ? a : b1[j];
                i1[j] = gt ? idxv : i1[j];
            }
        }
        // ---- odd step: compute on B, load s+2 into A ----
        {
            const unsigned char* ph = bh_base + (size_t)(s + 2) * 4096;
            const unsigned char* pl = bl_base + (size_t)(s + 2) * 4096;
            if (s + 2 < 128) {
                #pragma unroll
                for (int ks = 0; ks < 4; ++ks) {
                    bhA[ks] = *(const short8*)(ph + ks * 32);
                    blA[ks] = *(const short8*)(pl + ks * 32);
                }
                cbA = *(const f32x4*)(cb_base + (size_t)(s + 2) * 512);
            }

            f32x16 acc;
            #pragma unroll
            for (int q = 0; q < 16; ++q) acc[q] = cbB[q & 3];
            #pragma unroll
            for (int ks = 0; ks < 4; ++ks) acc = MFMA32(ah[ks], bhB[ks], acc);
            #pragma unroll
            for (int ks = 0; ks < 4; ++ks) acc = MFMA32(al[ks], bhB[ks], acc);
            #pragma unroll
            for (int ks = 0; ks < 4; ++ks) acc = MFMA32(ah[ks], blB[ks], acc);

            const int idxv = (s + 1) * 32 + colv;
            #pragma unroll
            for (int j = 0; j < 16; ++j) {
                const float a = acc[j];
                const bool gt = a > b1[j];
                b2[j] = fmaxf(b2[j], fminf(b1[j], a));
                b1[j] = gt ? a : b1[j];
                i1[j] = gt ? idxv : i1[j];
            }
        }
    }

    // cross-lane argmax over 32 code-columns, exact values, first-index tie-break
    int* bidx_lds = (int*)&sm[0];
    #pragma unroll
    for (int j = 0; j < 16; ++j) {
        float v1 = b1[j], v2 = b2[j]; int j1 = i1[j];
        #pragma unroll
        for (int msk = 1; msk < 32; msk <<= 1) {
            const float ov1 = __shfl_xor(v1, msk);
            const float ov2 = __shfl_xor(v2, msk);
            const int   oj1 = __shfl_xor(j1, msk);
            const bool take = (ov1 > v1) || (ov1 == v1 && oj1 < j1);
            const float nv2 = fmaxf(take ? v1 : v2, take ? ov2 : ov1);
            v1 = take ? ov1 : v1; j1 = take ? oj1 : j1; v2 = nv2;
        }
        if ((lane & 31) == 0) {
            const int rloc = wbase + (j & 3) + 8 * (j >> 2) + 4 * g;
            bidx_lds[rloc] = j1;
            if (v1 - v2 < EPS_M) {
                const int p = atomicAdd(counter, 1);
                list[p] = n0 + rloc;
            }
        }
    }
    __syncthreads();

    // fused gather: write both output slices for this block's 128 rows
    const float4* cb4 = (const float4*)cb;
    float4* out4 = (float4*)out;
    #pragma unroll
    for (int p = 0; p < 8; ++p) {
        const int id  = t + p * 256;       // 2048 = 128 rows * 16 chunks
        const int row = id >> 4, c4 = id & 15;
        const int k = bidx_lds[row];
        const float4 v = cb4[(size_t)k * 16 + c4];
        out4[(size_t)(n0 + row) * 16 + c4] = v;
        out4[(size_t)N_ROWS * 16 + (size_t)(n0 + row) * 16 + c4] = v;
    }
}

// ---- repair: exact fp32 argmin for flagged rows; rewrites their outputs ----
__global__ __launch_bounds__(256)
void repair_kernel(const float* __restrict__ z, const float* __restrict__ cb,
                   const float* __restrict__ csq, const int* __restrict__ list,
                   const int* __restrict__ counter, float* __restrict__ out) {
    __shared__ float xs[64];
    __shared__ float rv[4];
    __shared__ int   ri[4];
    __shared__ int   fi_s;
    const int cnt = counter[0];
    const int t = threadIdx.x;
    for (int e = blockIdx.x; e < cnt; e += gridDim.x) {
        const int row = list[e];
        __syncthreads();
        if (t < 64) xs[t] = z[(size_t)row * D_DIM + t];
        __syncthreads();
        float bv = __builtin_inff(); int bi = 0x7fffffff;
        for (int k = t; k < K_CB; k += 256) {
            const float4* cr = (const float4*)(cb + (size_t)k * D_DIM);
            float dot = 0.f;
            #pragma unroll
            for (int i = 0; i < 16; ++i) {
                float4 v = cr[i];
                dot = fmaf(v.x, xs[i * 4 + 0], dot);
                dot = fmaf(v.y, xs[i * 4 + 1], dot);
                dot = fmaf(v.z, xs[i * 4 + 2], dot);
                dot = fmaf(v.w, xs[i * 4 + 3], dot);
            }
            const float d = fmaf(dot, -2.f, csq[k]);
            if (d < bv) { bv = d; bi = k; }
        }
        #pragma unroll
        for (int msk = 1; msk < 64; msk <<= 1) {
            const float ov = __shfl_xor(bv, msk);
            const int   oi = __shfl_xor(bi, msk);
            if (ov < bv || (ov == bv && oi < bi)) { bv = ov; bi = oi; }
        }
        if ((t & 63) == 0) { rv[t >> 6] = bv; ri[t >> 6] = bi; }
        __syncthreads();
        if (t == 0) {
            float fb = rv[0]; int fi = ri[0];
            #pragma unroll
            for (int w = 1; w < 4; ++w)
                if (rv[w] < fb || (rv[w] == fb && ri[w] < fi)) { fb = rv[w]; fi = ri[w]; }
            fi_s = fi;
        }
        __syncthreads();
        if (t < 32) {
            const int dest = t >> 4, c4 = t & 15;
            const float4 v = ((const float4*)cb)[(size_t)fi_s * 16 + c4];
            float4* dst = (float4*)out + (size_t)dest * N_ROWS * 16 + (size_t)row * 16 + c4;
            *dst = v;
        }
        __syncthreads();
    }
}

extern "C" void kernel_launch(void* const* d_in, const int* in_sizes, int n_in,
                              void* d_out, int out_size, void* d_ws, size_t ws_size,
                              hipStream_t stream) {
    const float* z  = (const float*)d_in[0];
    const float* cb = (const float*)d_in[1];
    float* out = (float*)d_out;
    unsigned char* ws = (unsigned char*)d_ws;

    int*    counter = (int*)(ws + CTR_OFF);
    float*  csq     = (float*)(ws + CSQ_OFF);
    float4* cbias4  = (float4*)(ws + CB4_OFF);
    unsigned char* cbh = ws + CBH_OFF;
    unsigned char* cbl = ws + CBL_OFF;
    int* list  = (int*)(ws + LIST_OFF);

    prep_csq<<<K_CB / 256, 256, 0, stream>>>(cb, csq, cbias4, counter);
    prep_split<<<(K_CB * 8) / 256, 256, 0, stream>>>(cb, cbh, cbl);
    vq_main_mfma<<<N_ROWS / 128, 256, 0, stream>>>(z, cb, cbh, cbl, (const float*)cbias4,
                                                   list, counter, out);
    repair_kernel<<<2048, 256, 0, stream>>>(z, cb, csq, list, counter, out);
}

// Round 8
// 405.407 us; speedup vs baseline: 1.3111x; 1.3111x over previous
//
#include <hip/hip_runtime.h>

typedef __attribute__((ext_vector_type(8)))  short short8;   // 8 x bf16 fragment
typedef __attribute__((ext_vector_type(4)))  float f32x4;
typedef __attribute__((ext_vector_type(16))) float f32x16;

constexpr int N_ROWS = 131072;
constexpr int K_CB   = 4096;
constexpr int D_DIM  = 64;
constexpr float EPS_M = 1.25e-3f;   // margin in m-units (= 2.5e-3 in d = |x-c|^2 units)

// ---- ws layout (bytes) ----
constexpr size_t CTR_OFF   = 0;                         // int counter
constexpr size_t CSQ_OFF   = 64;                        // 4096 f32 (|c|^2, for repair)
constexpr size_t CB4_OFF   = CSQ_OFF + 16384;           // 4096 x 4 f32 (-0.5|c|^2 replicated)
constexpr size_t CBH_OFF   = CB4_OFF + 65536;           // 4096*64 bf16 hi, pre-swizzled
constexpr size_t CBL_OFF   = CBH_OFF + 524288;          // lo plane, pre-swizzled
constexpr size_t LIST_OFF  = CBL_OFF + 524288;          // flagged-row list

#define MFMA32(a, b, c) __builtin_amdgcn_mfma_f32_32x32x16_bf16((a), (b), (c), 0, 0, 0)

constexpr int BUF_BYTES = 17408;   // hi 8K | lo 8K | cbias 1K

__device__ __forceinline__ unsigned short f2bf(float f) {
    unsigned int u = __builtin_bit_cast(unsigned int, f);
    u = (u + 0x7fffu + ((u >> 16) & 1u)) >> 16;   // RTNE
    return (unsigned short)u;
}
__device__ __forceinline__ float bf2f(unsigned short h) {
    return __builtin_bit_cast(float, ((unsigned int)h) << 16);
}

// swizzled 16B fragment read from a [rows][128B] tile; chunk (2*ks+g) XOR (row&7)
__device__ __forceinline__ short8 ldfrag32(const unsigned char* base, int row, int g, int ks) {
    const int slot = ((2 * ks + g) ^ (row & 7));
    uint4 v = *(const uint4*)(base + row * 128 + slot * 16);
    return __builtin_bit_cast(short8, v);
}

// ---- prep: |c|^2 + replicated -0.5|c|^2 + counter init ----
__global__ __launch_bounds__(256)
void prep_csq(const float* __restrict__ cb, float* __restrict__ csq,
              float4* __restrict__ cbias4, int* __restrict__ counter) {
    const int k = blockIdx.x * 256 + threadIdx.x;
    if (k == 0) *counter = 0;
    const float4* row = (const float4*)(cb + (size_t)k * D_DIM);
    float s = 0.f;
    #pragma unroll
    for (int i = 0; i < 16; ++i) {
        float4 v = row[i];
        s = fmaf(v.x, v.x, s); s = fmaf(v.y, v.y, s);
        s = fmaf(v.z, v.z, s); s = fmaf(v.w, v.w, s);
    }
    csq[k] = s;
    const float n = -0.5f * s;
    cbias4[k] = make_float4(n, n, n, n);
}

// ---- prep: split cb into hi/lo bf16 planes, PRE-SWIZZLED (slot ^= row&7) ----
__global__ __launch_bounds__(256)
void prep_split(const float* __restrict__ cb, unsigned char* __restrict__ cbh,
                unsigned char* __restrict__ cbl) {
    const int id  = blockIdx.x * 256 + threadIdx.x;   // 32768 = 4096 rows * 8 chunks
    const int row = id >> 3, s = id & 7;
    const float4* src = (const float4*)(cb + (size_t)row * D_DIM + s * 8);
    float4 v0 = src[0], v1 = src[1];
    float f[8] = {v0.x, v0.y, v0.z, v0.w, v1.x, v1.y, v1.z, v1.w};
    unsigned int hw[4], lw[4];
    #pragma unroll
    for (int i = 0; i < 4; ++i) {
        unsigned short h0 = f2bf(f[2*i]),     l0 = f2bf(f[2*i]     - bf2f(h0));
        unsigned short h1 = f2bf(f[2*i + 1]), l1 = f2bf(f[2*i + 1] - bf2f(h1));
        hw[i] = (unsigned int)h0 | ((unsigned int)h1 << 16);
        lw[i] = (unsigned int)l0 | ((unsigned int)l1 << 16);
    }
    const int slot = s ^ (row & 7);
    *(uint4*)(cbh + (size_t)row * 128 + slot * 16) = make_uint4(hw[0], hw[1], hw[2], hw[3]);
    *(uint4*)(cbl + (size_t)row * 128 + slot * 16) = make_uint4(lw[0], lw[1], lw[2], lw[3]);
}

// ---- stage one 64-code tile: hi 8K | lo 8K | cbias 1K — 5 loads per wave, uniform ----
__device__ __forceinline__ void stage_tile(const unsigned char* __restrict__ cbh,
                                           const unsigned char* __restrict__ cbl,
                                           const float4* __restrict__ cbias4,
                                           unsigned char* sm, int T, int wid, int lane) {
    const unsigned char* sh = cbh + (size_t)T * 8192;
    const unsigned char* sl = cbl + (size_t)T * 8192;
    #pragma unroll
    for (int p = 0; p < 2; ++p) {
        const int chunk = wid * 2 + p;
        __builtin_amdgcn_global_load_lds(
            (const __attribute__((address_space(1))) void*)(sh + chunk * 1024 + lane * 16),
            (__attribute__((address_space(3))) void*)(sm + chunk * 1024), 16, 0, 0);
        __builtin_amdgcn_global_load_lds(
            (const __attribute__((address_space(1))) void*)(sl + chunk * 1024 + lane * 16),
            (__attribute__((address_space(3))) void*)(sm + 8192 + chunk * 1024), 16, 0, 0);
    }
    __builtin_amdgcn_global_load_lds(
        (const __attribute__((address_space(1))) void*)
            ((const unsigned char*)cbias4 + (size_t)T * 1024 + wid * 256 + lane * 4),
        (__attribute__((address_space(3))) void*)(sm + 16384 + wid * 256), 4, 0, 0);
}

// ---- main: counted-vmcnt double-buffer pipeline, 3-term split-bf16 32x32 MFMA ----
__global__ __launch_bounds__(256, 3)
void vq_main_mfma(const float* __restrict__ z,
                  const float* __restrict__ cb,
                  const unsigned char* __restrict__ cbh,
                  const unsigned char* __restrict__ cbl,
                  const float4* __restrict__ cbias4,
                  int* __restrict__ list,
                  int* __restrict__ counter, float* __restrict__ out) {
    __shared__ __align__(16) unsigned char sm[2][BUF_BYTES];   // 34816 B
    unsigned char* smf = &sm[0][0];
    const int t = threadIdx.x, lane = t & 63, wid = t >> 6;
    const int g = lane >> 5, colv = lane & 31;
    const int n0 = blockIdx.x * 128;
    const int wbase = wid * 32;

    // ---- stage A tile (128 rows of z) hi/lo swizzled into LDS (spans both buffers) ----
    #pragma unroll
    for (int p = 0; p < 4; ++p) {
        const int id = t + p * 256;          // 1024 = 128 rows * 8 chunks
        const int row = id >> 3, s = id & 7;
        const float4* src = (const float4*)(z + (size_t)(n0 + row) * D_DIM + s * 8);
        float4 v0 = src[0], v1 = src[1];
        float f[8] = {v0.x, v0.y, v0.z, v0.w, v1.x, v1.y, v1.z, v1.w};
        unsigned int hw[4], lw[4];
        #pragma unroll
        for (int i = 0; i < 4; ++i) {
            unsigned short h0 = f2bf(f[2*i]),     l0 = f2bf(f[2*i]     - bf2f(h0));
            unsigned short h1 = f2bf(f[2*i + 1]), l1 = f2bf(f[2*i + 1] - bf2f(h1));
            hw[i] = (unsigned int)h0 | ((unsigned int)h1 << 16);
            lw[i] = (unsigned int)l0 | ((unsigned int)l1 << 16);
        }
        const int slot = s ^ (row & 7);
        *(uint4*)(&smf[row * 128 + slot * 16])         = make_uint4(hw[0], hw[1], hw[2], hw[3]);
        *(uint4*)(&smf[16384 + row * 128 + slot * 16]) = make_uint4(lw[0], lw[1], lw[2], lw[3]);
    }
    __syncthreads();

    short8 ah[4], al[4];
    {
        const int arow = wbase + colv;
        #pragma unroll
        for (int ks = 0; ks < 4; ++ks) {
            ah[ks] = ldfrag32(smf,         arow, g, ks);
            al[ks] = ldfrag32(smf + 16384, arow, g, ks);
        }
    }
    __syncthreads();   // all waves done reading A; buffers free for B staging

    // per-lane fragment-read offsets (kernel-invariant): reg + immediate ds_reads
    int v_off[4];
    #pragma unroll
    for (int ks = 0; ks < 4; ++ks)
        v_off[ks] = (((2 * ks + g) ^ (colv & 7)) * 16) + colv * 128;
    const int cb_off = colv * 16;

    float b1[16], b2[16]; int i1[16];
    #pragma unroll
    for (int j = 0; j < 16; ++j) {
        b1[j] = -__builtin_inff(); b2[j] = -__builtin_inff(); i1[j] = 0;
    }

#define COMPUTE_TILE(BUF, TID)                                                      \
    do {                                                                            \
        const unsigned char* bp = smf + (BUF) * BUF_BYTES;                          \
        _Pragma("unroll")                                                           \
        for (int ct = 0; ct < 2; ++ct) {                                            \
            short8 bh[4], bl[4];                                                    \
            _Pragma("unroll")                                                       \
            for (int ks = 0; ks < 4; ++ks) {                                        \
                bh[ks] = __builtin_bit_cast(short8,                                 \
                    *(const uint4*)(bp + v_off[ks] + ct * 4096));                   \
                bl[ks] = __builtin_bit_cast(short8,                                 \
                    *(const uint4*)(bp + 8192 + v_off[ks] + ct * 4096));            \
            }                                                                       \
            const f32x4 cbv = *(const f32x4*)(bp + 16384 + ct * 512 + cb_off);      \
            f32x16 acc;                                                             \
            _Pragma("unroll")                                                       \
            for (int q = 0; q < 16; ++q) acc[q] = cbv[q & 3];                       \
            __builtin_amdgcn_s_setprio(1);                                          \
            _Pragma("unroll")                                                       \
            for (int ks = 0; ks < 4; ++ks) acc = MFMA32(ah[ks], bh[ks], acc);       \
            _Pragma("unroll")                                                       \
            for (int ks = 0; ks < 4; ++ks) acc = MFMA32(al[ks], bh[ks], acc);       \
            _Pragma("unroll")                                                       \
            for (int ks = 0; ks < 4; ++ks) acc = MFMA32(ah[ks], bl[ks], acc);       \
            __builtin_amdgcn_s_setprio(0);                                          \
            const int idxv = (TID) * 64 + ct * 32 + colv;                           \
            _Pragma("unroll")                                                       \
            for (int j = 0; j < 16; ++j) {                                          \
                const float a = acc[j];                                             \
                const bool gt = a > b1[j];                                          \
                b2[j] = fmaxf(b2[j], fminf(b1[j], a));                              \
                b1[j] = gt ? a : b1[j];                                             \
                i1[j] = gt ? idxv : i1[j];                                          \
            }                                                                       \
        }                                                                           \
    } while (0)

    // prologue: stage tile 0 into buf0
    stage_tile(cbh, cbl, cbias4, smf, 0, wid, lane);

    for (int T = 0; T < 64; T += 2) {
        // even phase: compute tile T from buf0
        __builtin_amdgcn_s_barrier();                      // all done reading buf1 (tile T-1)
        stage_tile(cbh, cbl, cbias4, smf + BUF_BYTES, T + 1, wid, lane);
        asm volatile("s_waitcnt vmcnt(5)" ::: "memory");   // my tile-T loads landed
        __builtin_amdgcn_s_barrier();                      // everyone's landed
        COMPUTE_TILE(0, T);
        // odd phase: compute tile T+1 from buf1
        __builtin_amdgcn_s_barrier();                      // all done reading buf0 (tile T)
        if (T + 2 < 64) {
            stage_tile(cbh, cbl, cbias4, smf, T + 2, wid, lane);
            asm volatile("s_waitcnt vmcnt(5)" ::: "memory");
        } else {
            asm volatile("s_waitcnt vmcnt(0)" ::: "memory");
        }
        __builtin_amdgcn_s_barrier();
        COMPUTE_TILE(1, T + 1);
    }
#undef COMPUTE_TILE

    __syncthreads();   // drain everything before LDS reuse

    // cross-lane argmax over 32 code-columns, exact values, first-index tie-break
    int* bidx_lds = (int*)&sm[0][0];
    #pragma unroll
    for (int j = 0; j < 16; ++j) {
        float v1 = b1[j], v2 = b2[j]; int j1 = i1[j];
        #pragma unroll
        for (int msk = 1; msk < 32; msk <<= 1) {
            const float ov1 = __shfl_xor(v1, msk);
            const float ov2 = __shfl_xor(v2, msk);
            const int   oj1 = __shfl_xor(j1, msk);
            const bool take = (ov1 > v1) || (ov1 == v1 && oj1 < j1);
            const float nv2 = fmaxf(take ? v1 : v2, take ? ov2 : ov1);
            v1 = take ? ov1 : v1; j1 = take ? oj1 : j1; v2 = nv2;
        }
        if ((lane & 31) == 0) {
            const int rloc = wbase + (j & 3) + 8 * (j >> 2) + 4 * g;
            bidx_lds[rloc] = j1;
            if (v1 - v2 < EPS_M) {
                const int p = atomicAdd(counter, 1);
                list[p] = n0 + rloc;
            }
        }
    }
    __syncthreads();

    // fused gather: write both output slices for this block's 128 rows
    const float4* cb4 = (const float4*)cb;
    float4* out4 = (float4*)out;
    #pragma unroll
    for (int p = 0; p < 8; ++p) {
        const int id  = t + p * 256;       // 2048 = 128 rows * 16 chunks
        const int row = id >> 4, c4 = id & 15;
        const int k = bidx_lds[row];
        const float4 v = cb4[(size_t)k * 16 + c4];
        out4[(size_t)(n0 + row) * 16 + c4] = v;
        out4[(size_t)N_ROWS * 16 + (size_t)(n0 + row) * 16 + c4] = v;
    }
}

// ---- repair: exact fp32 argmin for flagged rows (x register-resident, coalesced) ----
__global__ __launch_bounds__(256)
void repair_kernel(const float* __restrict__ z, const float* __restrict__ cb,
                   const float* __restrict__ csq, const int* __restrict__ list,
                   const int* __restrict__ counter, float* __restrict__ out) {
    __shared__ float4 xs4[16];
    __shared__ float rv[4];
    __shared__ int   ri[4];
    __shared__ int   fi_s;
    const int cnt = counter[0];
    const int t = threadIdx.x;
    for (int e = blockIdx.x; e < cnt; e += gridDim.x) {
        const int row = list[e];
        __syncthreads();
        if (t < 16) xs4[t] = ((const float4*)(z + (size_t)row * D_DIM))[t];
        __syncthreads();
        float4 xr[16];
        #pragma unroll
        for (int i = 0; i < 16; ++i) xr[i] = xs4[i];   // LDS broadcast -> registers
        float bv = __builtin_inff(); int bi = 0;
        #pragma unroll 2
        for (int i = 0; i < 16; ++i) {
            const int k = i * 256 + t;                 // coalesced across threads
            const float4* cr = (const float4*)(cb + (size_t)k * D_DIM);
            float dot = 0.f;
            #pragma unroll
            for (int q = 0; q < 16; ++q) {
                const float4 v = cr[q];
                dot = fmaf(v.x, xr[q].x, dot);
                dot = fmaf(v.y, xr[q].y, dot);
                dot = fmaf(v.z, xr[q].z, dot);
                dot = fmaf(v.w, xr[q].w, dot);
            }
            const float d = fmaf(dot, -2.f, csq[k]);
            if (d < bv) { bv = d; bi = k; }
        }
        #pragma unroll
        for (int msk = 1; msk < 64; msk <<= 1) {
            const float ov = __shfl_xor(bv, msk);
            const int   oi = __shfl_xor(bi, msk);
            if (ov < bv || (ov == bv && oi < bi)) { bv = ov; bi = oi; }
        }
        if ((t & 63) == 0) { rv[t >> 6] = bv; ri[t >> 6] = bi; }
        __syncthreads();
        if (t == 0) {
            float fb = rv[0]; int fi = ri[0];
            #pragma unroll
            for (int w = 1; w < 4; ++w)
                if (rv[w] < fb || (rv[w] == fb && ri[w] < fi)) { fb = rv[w]; fi = ri[w]; }
            fi_s = fi;
        }
        __syncthreads();
        if (t < 32) {
            const int dest = t >> 4, c4 = t & 15;
            const float4 v = ((const float4*)cb)[(size_t)fi_s * 16 + c4];
            float4* dst = (float4*)out + (size_t)dest * N_ROWS * 16 + (size_t)row * 16 + c4;
            *dst = v;
        }
        __syncthreads();
    }
}

extern "C" void kernel_launch(void* const* d_in, const int* in_sizes, int n_in,
                              void* d_out, int out_size, void* d_ws, size_t ws_size,
                              hipStream_t stream) {
    const float* z  = (const float*)d_in[0];
    const float* cb = (const float*)d_in[1];
    float* out = (float*)d_out;
    unsigned char* ws = (unsigned char*)d_ws;

    int*    counter = (int*)(ws + CTR_OFF);
    float*  csq     = (float*)(ws + CSQ_OFF);
    float4* cbias4  = (float4*)(ws + CB4_OFF);
    unsigned char* cbh = ws + CBH_OFF;
    unsigned char* cbl = ws + CBL_OFF;
    int* list  = (int*)(ws + LIST_OFF);

    prep_csq<<<K_CB / 256, 256, 0, stream>>>(cb, csq, cbias4, counter);
    prep_split<<<(K_CB * 8) / 256, 256, 0, stream>>>(cb, cbh, cbl);
    vq_main_mfma<<<N_ROWS / 128, 256, 0, stream>>>(z, cb, cbh, cbl, cbias4,
                                                   list, counter, out);
    repair_kernel<<<2048, 256, 0, stream>>>(z, cb, csq, list, counter, out);
}

// Round 9
// 283.203 us; speedup vs baseline: 1.8768x; 1.4315x over previous
//
#include <hip/hip_runtime.h>

typedef __attribute__((ext_vector_type(8)))  short short8;   // 8 x bf16 fragment
typedef __attribute__((ext_vector_type(4)))  float f32x4;
typedef __attribute__((ext_vector_type(16))) float f32x16;

constexpr int N_ROWS = 131072;
constexpr int K_CB   = 4096;
constexpr int D_DIM  = 64;
// key scale: m * 32768 truncated; granularity 3.05e-5 in m-units
constexpr float KEY_SCALE = 32768.0f;
// flag threshold in key-value units: 1.25e-3 m-units * 32768 = 41, +2 trunc slack -> 48
constexpr int EPS_KEY = 48;

// ---- ws layout (bytes) ----
constexpr size_t CTR_OFF   = 0;                         // int counter
constexpr size_t CSQ_OFF   = 64;                        // 4096 f32 (|c|^2, for repair)
constexpr size_t CB4_OFF   = CSQ_OFF + 16384;           // 4096 x 4 f32 (-0.5|c|^2 replicated)
constexpr size_t CBH_OFF   = CB4_OFF + 65536;           // 4096*64 bf16 hi, pre-swizzled
constexpr size_t CBL_OFF   = CBH_OFF + 524288;          // lo plane, pre-swizzled
constexpr size_t LIST_OFF  = CBL_OFF + 524288;          // flagged-row list

#define MFMA32(a, b, c) __builtin_amdgcn_mfma_f32_32x32x16_bf16((a), (b), (c), 0, 0, 0)

constexpr int BUF_BYTES = 17408;   // hi 8K | lo 8K | cbias 1K

__device__ __forceinline__ unsigned short f2bf(float f) {
    unsigned int u = __builtin_bit_cast(unsigned int, f);
    u = (u + 0x7fffu + ((u >> 16) & 1u)) >> 16;   // RTNE
    return (unsigned short)u;
}
__device__ __forceinline__ float bf2f(unsigned short h) {
    return __builtin_bit_cast(float, ((unsigned int)h) << 16);
}
__device__ __forceinline__ int med3_i32(int a, int b, int c) {
    int r;
    asm("v_med3_i32 %0, %1, %2, %3" : "=v"(r) : "v"(a), "v"(b), "v"(c));
    return r;
}
__device__ __forceinline__ int imax(int a, int b) { return a > b ? a : b; }

// swizzled 16B fragment read from a [rows][128B] tile; chunk (2*ks+g) XOR (row&7)
__device__ __forceinline__ short8 ldfrag32(const unsigned char* base, int row, int g, int ks) {
    const int slot = ((2 * ks + g) ^ (row & 7));
    uint4 v = *(const uint4*)(base + row * 128 + slot * 16);
    return __builtin_bit_cast(short8, v);
}

// ---- prep: |c|^2 + replicated -0.5|c|^2 + counter init ----
__global__ __launch_bounds__(256)
void prep_csq(const float* __restrict__ cb, float* __restrict__ csq,
              float4* __restrict__ cbias4, int* __restrict__ counter) {
    const int k = blockIdx.x * 256 + threadIdx.x;
    if (k == 0) *counter = 0;
    const float4* row = (const float4*)(cb + (size_t)k * D_DIM);
    float s = 0.f;
    #pragma unroll
    for (int i = 0; i < 16; ++i) {
        float4 v = row[i];
        s = fmaf(v.x, v.x, s); s = fmaf(v.y, v.y, s);
        s = fmaf(v.z, v.z, s); s = fmaf(v.w, v.w, s);
    }
    csq[k] = s;
    const float n = -0.5f * s;
    cbias4[k] = make_float4(n, n, n, n);
}

// ---- prep: split cb into hi/lo bf16 planes, PRE-SWIZZLED (slot ^= row&7) ----
__global__ __launch_bounds__(256)
void prep_split(const float* __restrict__ cb, unsigned char* __restrict__ cbh,
                unsigned char* __restrict__ cbl) {
    const int id  = blockIdx.x * 256 + threadIdx.x;   // 32768 = 4096 rows * 8 chunks
    const int row = id >> 3, s = id & 7;
    const float4* src = (const float4*)(cb + (size_t)row * D_DIM + s * 8);
    float4 v0 = src[0], v1 = src[1];
    float f[8] = {v0.x, v0.y, v0.z, v0.w, v1.x, v1.y, v1.z, v1.w};
    unsigned int hw[4], lw[4];
    #pragma unroll
    for (int i = 0; i < 4; ++i) {
        unsigned short h0 = f2bf(f[2*i]),     l0 = f2bf(f[2*i]     - bf2f(h0));
        unsigned short h1 = f2bf(f[2*i + 1]), l1 = f2bf(f[2*i + 1] - bf2f(h1));
        hw[i] = (unsigned int)h0 | ((unsigned int)h1 << 16);
        lw[i] = (unsigned int)l0 | ((unsigned int)l1 << 16);
    }
    const int slot = s ^ (row & 7);
    *(uint4*)(cbh + (size_t)row * 128 + slot * 16) = make_uint4(hw[0], hw[1], hw[2], hw[3]);
    *(uint4*)(cbl + (size_t)row * 128 + slot * 16) = make_uint4(lw[0], lw[1], lw[2], lw[3]);
}

// ---- stage one 64-code tile: hi 8K | lo 8K | cbias 1K — 5 loads per wave, uniform ----
__device__ __forceinline__ void stage_tile(const unsigned char* __restrict__ cbh,
                                           const unsigned char* __restrict__ cbl,
                                           const float4* __restrict__ cbias4,
                                           unsigned char* sm, int T, int wid, int lane) {
    const unsigned char* sh = cbh + (size_t)T * 8192;
    const unsigned char* sl = cbl + (size_t)T * 8192;
    #pragma unroll
    for (int p = 0; p < 2; ++p) {
        const int chunk = wid * 2 + p;
        __builtin_amdgcn_global_load_lds(
            (const __attribute__((address_space(1))) void*)(sh + chunk * 1024 + lane * 16),
            (__attribute__((address_space(3))) void*)(sm + chunk * 1024), 16, 0, 0);
        __builtin_amdgcn_global_load_lds(
            (const __attribute__((address_space(1))) void*)(sl + chunk * 1024 + lane * 16),
            (__attribute__((address_space(3))) void*)(sm + 8192 + chunk * 1024), 16, 0, 0);
    }
    __builtin_amdgcn_global_load_lds(
        (const __attribute__((address_space(1))) void*)
            ((const unsigned char*)cbias4 + (size_t)T * 1024 + wid * 256 + lane * 4),
        (__attribute__((address_space(3))) void*)(sm + 16384 + wid * 256), 4, 0, 0);
}

// ---- main: counted-vmcnt pipeline + int-packed-key top-2 (32 regs of state) ----
__global__ __launch_bounds__(256, 3)
void vq_main_mfma(const float* __restrict__ z,
                  const float* __restrict__ cb,
                  const unsigned char* __restrict__ cbh,
                  const unsigned char* __restrict__ cbl,
                  const float4* __restrict__ cbias4,
                  int* __restrict__ list,
                  int* __restrict__ counter, float* __restrict__ out) {
    __shared__ __align__(16) unsigned char sm[2][BUF_BYTES];   // 34816 B
    unsigned char* smf = &sm[0][0];
    const int t = threadIdx.x, lane = t & 63, wid = t >> 6;
    const int g = lane >> 5, colv = lane & 31;
    const int n0 = blockIdx.x * 128;
    const int wbase = wid * 32;

    // ---- stage A tile (128 rows of z) hi/lo swizzled into LDS (spans both buffers) ----
    #pragma unroll
    for (int p = 0; p < 4; ++p) {
        const int id = t + p * 256;          // 1024 = 128 rows * 8 chunks
        const int row = id >> 3, s = id & 7;
        const float4* src = (const float4*)(z + (size_t)(n0 + row) * D_DIM + s * 8);
        float4 v0 = src[0], v1 = src[1];
        float f[8] = {v0.x, v0.y, v0.z, v0.w, v1.x, v1.y, v1.z, v1.w};
        unsigned int hw[4], lw[4];
        #pragma unroll
        for (int i = 0; i < 4; ++i) {
            unsigned short h0 = f2bf(f[2*i]),     l0 = f2bf(f[2*i]     - bf2f(h0));
            unsigned short h1 = f2bf(f[2*i + 1]), l1 = f2bf(f[2*i + 1] - bf2f(h1));
            hw[i] = (unsigned int)h0 | ((unsigned int)h1 << 16);
            lw[i] = (unsigned int)l0 | ((unsigned int)l1 << 16);
        }
        const int slot = s ^ (row & 7);
        *(uint4*)(&smf[row * 128 + slot * 16])         = make_uint4(hw[0], hw[1], hw[2], hw[3]);
        *(uint4*)(&smf[16384 + row * 128 + slot * 16]) = make_uint4(lw[0], lw[1], lw[2], lw[3]);
    }
    __syncthreads();

    short8 ah[4], al[4];
    {
        const int arow = wbase + colv;
        #pragma unroll
        for (int ks = 0; ks < 4; ++ks) {
            ah[ks] = ldfrag32(smf,         arow, g, ks);
            al[ks] = ldfrag32(smf + 16384, arow, g, ks);
        }
    }
    __syncthreads();   // all waves done reading A; buffers free for B staging

    // per-lane fragment-read offsets (kernel-invariant): reg + immediate ds_reads
    int v_off[4];
    #pragma unroll
    for (int ks = 0; ks < 4; ++ks)
        v_off[ks] = (((2 * ks + g) ^ (colv & 7)) * 16) + colv * 128;
    const int cb_off = colv * 16;

    // packed-key top-2 state: 32 VGPRs total, no index array
    int k1[16], k2[16];
    #pragma unroll
    for (int j = 0; j < 16; ++j) { k1[j] = INT_MIN; k2[j] = INT_MIN; }

#define COMPUTE_TILE(BUF, TID)                                                      \
    do {                                                                            \
        const unsigned char* bp = smf + (BUF) * BUF_BYTES;                          \
        const int inv0 = 127 - (TID) * 2;                                           \
        int keyA[16];                                                               \
        _Pragma("unroll")                                                           \
        for (int ct = 0; ct < 2; ++ct) {                                            \
            short8 bh[4], bl[4];                                                    \
            _Pragma("unroll")                                                       \
            for (int ks = 0; ks < 4; ++ks) {                                        \
                bh[ks] = __builtin_bit_cast(short8,                                 \
                    *(const uint4*)(bp + v_off[ks] + ct * 4096));                   \
                bl[ks] = __builtin_bit_cast(short8,                                 \
                    *(const uint4*)(bp + 8192 + v_off[ks] + ct * 4096));            \
            }                                                                       \
            const f32x4 cbv = *(const f32x4*)(bp + 16384 + ct * 512 + cb_off);      \
            f32x16 acc;                                                             \
            _Pragma("unroll")                                                       \
            for (int q = 0; q < 16; ++q) acc[q] = cbv[q & 3];                       \
            __builtin_amdgcn_s_setprio(1);                                          \
            _Pragma("unroll")                                                       \
            for (int ks = 0; ks < 4; ++ks) acc = MFMA32(ah[ks], bh[ks], acc);       \
            _Pragma("unroll")                                                       \
            for (int ks = 0; ks < 4; ++ks) acc = MFMA32(al[ks], bh[ks], acc);       \
            _Pragma("unroll")                                                       \
            for (int ks = 0; ks < 4; ++ks) acc = MFMA32(ah[ks], bl[ks], acc);       \
            __builtin_amdgcn_s_setprio(0);                                          \
            if (ct == 0) {                                                          \
                _Pragma("unroll")                                                   \
                for (int j = 0; j < 16; ++j)                                        \
                    keyA[j] = ((int)(acc[j] * KEY_SCALE) << 7) | inv0;              \
            } else {                                                                \
                _Pragma("unroll")                                                   \
                for (int j = 0; j < 16; ++j) {                                      \
                    const int kB = ((int)(acc[j] * KEY_SCALE) << 7) | (inv0 - 1);   \
                    const int med = med3_i32(k1[j], keyA[j], kB);                   \
                    k1[j] = imax(k1[j], imax(keyA[j], kB));                         \
                    k2[j] = imax(k2[j], med);                                       \
                }                                                                   \
            }                                                                       \
        }                                                                           \
    } while (0)

    // prologue: stage tile 0 into buf0
    stage_tile(cbh, cbl, cbias4, smf, 0, wid, lane);

    for (int T = 0; T < 64; T += 2) {
        // even phase: compute tile T from buf0
        __builtin_amdgcn_s_barrier();                      // all done reading buf1 (tile T-1)
        stage_tile(cbh, cbl, cbias4, smf + BUF_BYTES, T + 1, wid, lane);
        asm volatile("s_waitcnt vmcnt(5)" ::: "memory");   // my tile-T loads landed
        __builtin_amdgcn_s_barrier();                      // everyone's landed
        COMPUTE_TILE(0, T);
        // odd phase: compute tile T+1 from buf1
        __builtin_amdgcn_s_barrier();                      // all done reading buf0 (tile T)
        if (T + 2 < 64) {
            stage_tile(cbh, cbl, cbias4, smf, T + 2, wid, lane);
            asm volatile("s_waitcnt vmcnt(5)" ::: "memory");
        } else {
            asm volatile("s_waitcnt vmcnt(0)" ::: "memory");
        }
        __builtin_amdgcn_s_barrier();
        COMPUTE_TILE(1, T + 1);
    }
#undef COMPUTE_TILE

    __syncthreads();   // drain everything before LDS reuse

    // cross-lane argmax over 32 code-columns on packed keys
    int* bidx_lds = (int*)&sm[0][0];
    #pragma unroll
    for (int j = 0; j < 16; ++j) {
        int v1 = k1[j], v2 = k2[j]; int cj = colv;
        #pragma unroll
        for (int msk = 1; msk < 32; msk <<= 1) {
            const int ov1 = __shfl_xor(v1, msk);
            const int ov2 = __shfl_xor(v2, msk);
            const int oc  = __shfl_xor(cj, msk);
            const bool take = (ov1 > v1) || (ov1 == v1 && oc < cj);
            const int nv2 = imax(take ? v1 : v2, take ? ov2 : ov1);
            v1 = take ? ov1 : v1; cj = take ? oc : cj; v2 = nv2;
        }
        if ((lane & 31) == 0) {
            const int tc  = 127 - (v1 & 127);              // tile*2 + ct
            const int idx = tc * 32 + cj;
            const int rloc = wbase + (j & 3) + 8 * (j >> 2) + 4 * g;
            bidx_lds[rloc] = idx;
            if ((v1 >> 7) - (v2 >> 7) < EPS_KEY) {
                const int p = atomicAdd(counter, 1);
                list[p] = n0 + rloc;
            }
        }
    }
    __syncthreads();

    // fused gather: write both output slices for this block's 128 rows
    const float4* cb4 = (const float4*)cb;
    float4* out4 = (float4*)out;
    #pragma unroll
    for (int p = 0; p < 8; ++p) {
        const int id  = t + p * 256;       // 2048 = 128 rows * 16 chunks
        const int row = id >> 4, c4 = id & 15;
        const int k = bidx_lds[row];
        const float4 v = cb4[(size_t)k * 16 + c4];
        out4[(size_t)(n0 + row) * 16 + c4] = v;
        out4[(size_t)N_ROWS * 16 + (size_t)(n0 + row) * 16 + c4] = v;
    }
}

// ---- repair: exact fp32 argmin for flagged rows (x register-resident, coalesced) ----
__global__ __launch_bounds__(256)
void repair_kernel(const float* __restrict__ z, const float* __restrict__ cb,
                   const float* __restrict__ csq, const int* __restrict__ list,
                   const int* __restrict__ counter, float* __restrict__ out) {
    __shared__ float4 xs4[16];
    __shared__ float rv[4];
    __shared__ int   ri[4];
    __shared__ int   fi_s;
    const int cnt = counter[0];
    const int t = threadIdx.x;
    for (int e = blockIdx.x; e < cnt; e += gridDim.x) {
        const int row = list[e];
        __syncthreads();
        if (t < 16) xs4[t] = ((const float4*)(z + (size_t)row * D_DIM))[t];
        __syncthreads();
        float4 xr[16];
        #pragma unroll
        for (int i = 0; i < 16; ++i) xr[i] = xs4[i];   // LDS broadcast -> registers
        float bv = __builtin_inff(); int bi = 0;
        #pragma unroll 2
        for (int i = 0; i < 16; ++i) {
            const int k = i * 256 + t;                 // coalesced across threads
            const float4* cr = (const float4*)(cb + (size_t)k * D_DIM);
            float dot = 0.f;
            #pragma unroll
            for (int q = 0; q < 16; ++q) {
                const float4 v = cr[q];
                dot = fmaf(v.x, xr[q].x, dot);
                dot = fmaf(v.y, xr[q].y, dot);
                dot = fmaf(v.z, xr[q].z, dot);
                dot = fmaf(v.w, xr[q].w, dot);
            }
            const float d = fmaf(dot, -2.f, csq[k]);
            if (d < bv) { bv = d; bi = k; }
        }
        #pragma unroll
        for (int msk = 1; msk < 64; msk <<= 1) {
            const float ov = __shfl_xor(bv, msk);
            const int   oi = __shfl_xor(bi, msk);
            if (ov < bv || (ov == bv && oi < bi)) { bv = ov; bi = oi; }
        }
        if ((t & 63) == 0) { rv[t >> 6] = bv; ri[t >> 6] = bi; }
        __syncthreads();
        if (t == 0) {
            float fb = rv[0]; int fi = ri[0];
            #pragma unroll
            for (int w = 1; w < 4; ++w)
                if (rv[w] < fb || (rv[w] == fb && ri[w] < fi)) { fb = rv[w]; fi = ri[w]; }
            fi_s = fi;
        }
        __syncthreads();
        if (t < 32) {
            const int dest = t >> 4, c4 = t & 15;
            const float4 v = ((const float4*)cb)[(size_t)fi_s * 16 + c4];
            float4* dst = (float4*)out + (size_t)dest * N_ROWS * 16 + (size_t)row * 16 + c4;
            *dst = v;
        }
        __syncthreads();
    }
}

extern "C" void kernel_launch(void* const* d_in, const int* in_sizes, int n_in,
                              void* d_out, int out_size, void* d_ws, size_t ws_size,
                              hipStream_t stream) {
    const float* z  = (const float*)d_in[0];
    const float* cb = (const float*)d_in[1];
    float* out = (float*)d_out;
    unsigned char* ws = (unsigned char*)d_ws;

    int*    counter = (int*)(ws + CTR_OFF);
    float*  csq     = (float*)(ws + CSQ_OFF);
    float4* cbias4  = (float4*)(ws + CB4_OFF);
    unsigned char* cbh = ws + CBH_OFF;
    unsigned char* cbl = ws + CBL_OFF;
    int* list  = (int*)(ws + LIST_OFF);

    prep_csq<<<K_CB / 256, 256, 0, stream>>>(cb, csq, cbias4, counter);
    prep_split<<<(K_CB * 8) / 256, 256, 0, stream>>>(cb, cbh, cbl);
    vq_main_mfma<<<N_ROWS / 128, 256, 0, stream>>>(z, cb, cbh, cbl, cbias4,
                                                   list, counter, out);
    repair_kernel<<<2048, 256, 0, stream>>>(z, cb, csq, list, counter, out);
}